// Round 11
// baseline (275.200 us; speedup 1.0000x reference)
//
#include <hip/hip_runtime.h>
#include <hip/hip_bf16.h>
#include <cstdint>

#define NB    8
#define NPTS  4096
#define NQ    2              // col-halves (blockIdx.y)
#define NT    128            // cand tiles per half (2048/16)
#define PROW  32             // part row stride in u32 (2 halves x 16)
#define SENT  0xFF000000u    // sentinel key (> any real fixed-point key)
#define KNN_T 256            // k_knn block size (4 waves)

typedef __attribute__((ext_vector_type(8))) short bf16x8;
typedef __attribute__((ext_vector_type(4))) float f32x4;

// ---------------------------------------------------------------------------
// A: x [B,C,N] -> XT fp32 [B,N,64], XH/XL bf16 split, sq, sqn=128*sq+32768.
// (sqn is the 256x-scaled biased score init: 256*(0.5*sq + 128).)
// Fused: blockIdx.x==64 (y==0) builds G=[W1;W2-W1] bf16-split + BB=b1+b2.
// ---------------------------------------------------------------------------
__global__ __launch_bounds__(256) void k_prep(const float* __restrict__ x,
                                              const float* __restrict__ W1,
                                              const float* __restrict__ b1,
                                              const float* __restrict__ W2,
                                              const float* __restrict__ b2,
                                              float* __restrict__ xt,
                                              __hip_bfloat16* __restrict__ xh,
                                              __hip_bfloat16* __restrict__ xl,
                                              float* __restrict__ sq,
                                              float* __restrict__ sqn,
                                              __hip_bfloat16* __restrict__ gh,
                                              __hip_bfloat16* __restrict__ gl,
                                              float* __restrict__ bb) {
  const int t = threadIdx.x;
  if (blockIdx.x == 64) {                       // fused gsplit (one block)
    if (blockIdx.y != 0) return;
#pragma unroll 1
    for (int i = t; i < 128 * 64; i += 256) {
      int o = i >> 6, c = i & 63;
      float g = (o < 64) ? W1[o * 64 + c]
                         : (W2[(o - 64) * 64 + c] - W1[(o - 64) * 64 + c]);
      __hip_bfloat16 h = __float2bfloat16(g);
      gh[i] = h;
      gl[i] = __float2bfloat16(g - __bfloat162float(h));
    }
    if (t < 64) bb[t] = b1[t] + b2[t];
    return;
  }
  __shared__ float tile[64][65];
  const int b  = blockIdx.y;
  const int n0 = blockIdx.x * 64;
#pragma unroll
  for (int i = 0; i < 16; ++i) {
    int lin = i * 256 + t;
    int c = lin >> 6, j = lin & 63;
    tile[j][c] = x[(size_t)b * 64 * NPTS + (size_t)c * NPTS + n0 + j];
  }
  __syncthreads();
#pragma unroll
  for (int i = 0; i < 16; ++i) {
    int lin = i * 256 + t;
    int j = lin >> 6, c = lin & 63;
    float v = tile[j][c];
    size_t o = ((size_t)b * NPTS + n0 + j) * 64 + c;
    xt[o] = v;
    __hip_bfloat16 h = __float2bfloat16(v);
    xh[o] = h;
    xl[o] = __float2bfloat16(v - __bfloat162float(h));
  }
  if (t < 64) {
    float s = 0.f;
#pragma unroll
    for (int c = 0; c < 64; ++c) { float v = tile[t][c]; s = fmaf(v, v, s); }
    sq [b * NPTS + t + n0] = s;
    sqn[b * NPTS + t + n0] = fmaf(128.f, s, 32768.f);  // 256*(0.5*sq+128)
  }
}

// ---------------------------------------------------------------------------
// B: barrier-free-loop MFMA KNN (hh-only; exact rerank absorbs bf16 error).
// Score (256x-scaled, row term dropped): s = 32768 + 128*sq_m - 256*(x_r.x_m)
// > 0 always; FIXED-POINT KEY ki=(u32)s, key=(ki<<12)|m (quantum 1/128
// dist^2, 4x finer than the r1-4 float key that passed; r5 coarser FAILED).
// r11: OVERHEAD STRIP. k_knn is VALU-issue-volume bound (instr cut ->
// proportional time cut, r10). Deleted: per-tile 64-bit address recompute
// (one base pointer, +4096B per 2-tile group, loads at folded imm offsets
// 0/64/2048/2112B), prefetch rotation (loads get sunk anyway -- r9's true
// async pipeline was neutral, latency proven irrelevant), clamp logic.
// Selection machinery byte-identical to r10 (passed): 16-slot defer buffer,
// trigger >=9 per 8 inserts, bitonic flush, shared cross-quad threshold.
// launch_bounds(256,4): 128-VGPR cap. DO NOT demand more waves/EU: (256,8)
// forced a 32-VGPR squeeze -> scratch spill (WRITE 8MB->544MB, 3x slower).
// ---------------------------------------------------------------------------
__global__ __launch_bounds__(KNN_T, 4) void k_knn(const __hip_bfloat16* __restrict__ xh,
                                                  const float* __restrict__ sqn,
                                                  unsigned* __restrict__ part) {
  __shared__ unsigned bufu[17 * KNN_T];           // 17.4 KB defer (slot-major)
  __shared__ float    svb[2048];                  // 8 KB: half's sqn

  const int tid  = threadIdx.x;
  const int w    = tid >> 6;                      // wave -> 16-row tile
  const int lane = tid & 63;
  const int quad = lane >> 4, l15 = lane & 15;
  const int rb   = blockIdx.x;                    // 0..63 row-block (64 rows)
  const int q    = blockIdx.y;                    // 0..1 col-half
  const int b    = blockIdx.z;                    // 0..7
  const size_t xbase = (size_t)b * NPTS * 64;
  const int c0   = q * 2048;
  const int nrow = rb * 64 + w * 16 + l15;        // this lane's row

  // cooperative: half's sqn -> LDS (2048 floats, two float4 per thread)
  {
    const float4* src = (const float4*)(sqn + b * NPTS + c0);
    ((float4*)svb)[tid]       = src[tid];
    ((float4*)svb)[tid + 256] = src[tid + 256];
  }

  // persistent B-operand fragments: the wave's rows, scaled by -256:
  // bf16 bits: ^0x8000 (negate) then +0x0400 (exponent+8 = *256).
  const __hip_bfloat16* ph = xh + xbase + (size_t)nrow * 64 + quad * 8;
  bf16x8 rh0 = *(const bf16x8*)(ph);
  bf16x8 rh1 = *(const bf16x8*)(ph + 32);
  rh0 = (rh0 ^ (short)0x8000) + (short)0x0400;
  rh1 = (rh1 ^ (short)0x8000) + (short)0x0400;

  __syncthreads();                                // svb ready (only barrier)

  unsigned D[16];                                 // sorted ascending keys
#pragma unroll
  for (int i = 0; i < 16; ++i) D[i] = SENT;
  unsigned thr = SENT | 0xFFFu;
  int cnt = 0;

  auto flush = [&]() {
    unsigned E[16];
#pragma unroll
    for (int j = 0; j < 16; ++j) E[j] = bufu[j * KNN_T + tid];  // conflict-free
#pragma unroll
    for (int j = 0; j < 16; ++j) E[j] = (j < cnt) ? E[j] : 0xFFFFFFFFu;
    // bitonic full sort ascending (n=16) -- proven network
#pragma unroll
    for (int k = 2; k <= 16; k <<= 1)
#pragma unroll
      for (int j = k >> 1; j > 0; j >>= 1)
#pragma unroll
        for (int i = 0; i < 16; ++i) {
          int l = i ^ j;
          if (l > i) {
            unsigned lo = min(E[i], E[l]), hi = max(E[i], E[l]);
            bool up = ((i & k) == 0);
            E[i] = up ? lo : hi;
            E[l] = up ? hi : lo;
          }
        }
    // keep 16 smallest of D (asc) ∪ E (asc): reverse-min + bitonic clean
    unsigned T[16];
#pragma unroll
    for (int i = 0; i < 16; ++i) T[i] = min(D[i], E[15 - i]);
#pragma unroll
    for (int j = 8; j > 0; j >>= 1)
#pragma unroll
      for (int i = 0; i < 16; ++i) {
        int l = i ^ j;
        if (l > i) {
          unsigned lo = min(T[i], T[l]);
          T[l] = max(T[i], T[l]);
          T[i] = lo;
        }
      }
#pragma unroll
    for (int i = 0; i < 16; ++i) D[i] = T[i];
    cnt = 0;
    // shared threshold: min of D[15] across the row's 4 quads (rank-safe:
    // if D_q[15] < final union-16th, lane q alone holds 16 smaller keys --
    // contradiction; so discards exceed the final 16th, keeps never evicted)
    unsigned t0 = D[15] | 0xFFFu;
    unsigned t1 = min(t0, (unsigned)__shfl_xor((int)t0, 16));
    thr = min(t1, (unsigned)__shfl_xor((int)t1, 32));
  };

  // branchless insert: fixed-point key, dummy slot 16
  auto ins = [&](float s, int m) {
    unsigned ki  = (unsigned)s;                   // cvt_u32: trunc, monotone
    unsigned key = (ki << 12) | (unsigned)m;
    bool pass = (key <= thr);
    int slot = pass ? cnt : 16;
    bufu[slot * KNN_T + tid] = key;
    cnt += pass;
  };

  // running pointers: candidate frags for tile t at ap + t*1024 elems
  // (2048B); per 2-tile group advance +2048 elems, loads at folded imm
  // offsets 0 / 64 / 2048+0 / 2048+64 elems*2B.
  const __hip_bfloat16* ap = xh + xbase + (size_t)(c0 + l15) * 64 + quad * 8;
  const float* vp = svb + quad * 4;               // sv base, +32 floats/group

#pragma unroll 1
  for (int g = 0; g < NT / 2; ++g) {
    const bf16x8 h0 = *(const bf16x8*)(ap);
    const bf16x8 h1 = *(const bf16x8*)(ap + 32);
    const bf16x8 h2 = *(const bf16x8*)(ap + 1024);
    const bf16x8 h3 = *(const bf16x8*)(ap + 1056);
    f32x4 m1 = *(const f32x4*)(vp);
    f32x4 m3 = *(const f32x4*)(vp + 16);
    m1 = __builtin_amdgcn_mfma_f32_16x16x32_bf16(h0, rh0, m1, 0, 0, 0);
    m3 = __builtin_amdgcn_mfma_f32_16x16x32_bf16(h2, rh0, m3, 0, 0, 0);
    m1 = __builtin_amdgcn_mfma_f32_16x16x32_bf16(h1, rh1, m1, 0, 0, 0);
    m3 = __builtin_amdgcn_mfma_f32_16x16x32_bf16(h3, rh1, m3, 0, 0, 0);
    const int ca = c0 + g * 32 + quad * 4;
#pragma unroll
    for (int i = 0; i < 4; ++i) ins(m1[i], ca + i);
#pragma unroll
    for (int i = 0; i < 4; ++i) ins(m3[i], ca + 16 + i);
    if (__any(cnt >= 9)) flush();                 // +8/group -> never >16
    ap += 2048;
    vp += 32;
  }
  flush();

  // cross-quad merge: 2 rounds of shfl_xor bitonic top-16 merging
#pragma unroll
  for (int rd = 0; rd < 2; ++rd) {
    const int dx = (rd == 0) ? 16 : 32;
    unsigned Bx[16], T[16];
#pragma unroll
    for (int i = 0; i < 16; ++i) Bx[i] = (unsigned)__shfl_xor((int)D[i], dx);
#pragma unroll
    for (int i = 0; i < 16; ++i) T[i] = min(D[i], Bx[15 - i]);
#pragma unroll
    for (int j = 8; j > 0; j >>= 1)
#pragma unroll
      for (int i = 0; i < 16; ++i) {
        int l = i ^ j;
        if (l > i) {
          unsigned lo = min(T[i], T[l]);
          T[l] = max(T[i], T[l]);
          T[i] = lo;
        }
      }
#pragma unroll
    for (int i = 0; i < 16; ++i) D[i] = T[i];
  }
  if (quad == 0) {
    const size_t base = (size_t)(b * NPTS + nrow) * PROW + (size_t)q * 16;
#pragma unroll
    for (int i = 0; i < 16; ++i) part[base + i] = D[i];
  }
}

// ---------------------------------------------------------------------------
// C+D fused: merge 32 partial keys -> top-20 (LDS handoff) -> exact fp32
// rerank -> knn[16]. 32-lane group per row (1 key/lane), 8 rows per block.
// Keys globally distinct (index in low 12 bits, halves disjoint) -> ranks
// unique, slots 0..19 exactly filled.
// ---------------------------------------------------------------------------
__global__ __launch_bounds__(256) void k_mr(const unsigned* __restrict__ part,
                                            const float* __restrict__ xt,
                                            const float* __restrict__ sq,
                                            int* __restrict__ knn) {
  __shared__ unsigned short lc[8][20];
  const int g   = threadIdx.x >> 5;               // group 0..7
  const int c   = threadIdx.x & 31;
  const int row = blockIdx.x * 8 + g;
  // phase 1: rank 32 keys with 32 lanes (1 key/lane)
  const unsigned v = part[(size_t)row * PROW + c];
  int r = 0;
#pragma unroll
  for (int j = 0; j < 32; ++j) {
    unsigned a = (unsigned)__shfl((int)v, j, 32);
    r += (a < v);
  }
  if (r < 20) lc[g][r] = (unsigned short)(v & 0xFFFu);
  __syncthreads();
  // phase 2: exact fp32 rerank of the 20 candidates (lanes 0..19 active)
  const int b = row >> 12;
  const int m = lc[g][c < 20 ? c : 0];
  const float4* cr = (const float4*)(xt + (size_t)row * 64);
  const float4* mr = (const float4*)(xt + ((size_t)(b << 12) + m) * 64);
  float d = 0.f;
#pragma unroll
  for (int j = 0; j < 16; ++j) {
    float4 a = cr[j], vv = mr[j];
    d = fmaf(a.x, vv.x, d); d = fmaf(a.y, vv.y, d);
    d = fmaf(a.z, vv.z, d); d = fmaf(a.w, vv.w, d);
  }
  float key = sq[(b << 12) + m] - 2.f * d;          // exact fp32 rank key
  if (m == (row & 4095)) key = 1e30f;               // exclude self
  int rk = 0;
#pragma unroll
  for (int j = 0; j < 20; ++j) {
    float kj = __shfl(key, j, 32);
    int   mj = __shfl(m, j, 32);
    rk += (kj < key) || ((kj == key) && (mj < m));
  }
  if (c < 20 && rk < 16) knn[(size_t)row * 16 + rk] = m;
}

// ---------------------------------------------------------------------------
// E: MFMA P/Q GEMM. P = X·W1^T ; Q = X·(W2-W1)^T + (b1+b2), via G=[W1;W2-W1]
// bf16-split (hh+hl+lh). Wave = 16 rows x 128 outs (8 tiles, 48 MFMAs).
// ---------------------------------------------------------------------------
__global__ __launch_bounds__(256) void k_pq(const __hip_bfloat16* __restrict__ xh,
                                            const __hip_bfloat16* __restrict__ xl,
                                            const __hip_bfloat16* __restrict__ gh,
                                            const __hip_bfloat16* __restrict__ gl,
                                            const float* __restrict__ bb,
                                            float* __restrict__ P,
                                            float* __restrict__ Q) {
  const int tid  = threadIdx.x;
  const int w    = tid >> 6;
  const int lane = tid & 63;
  const int quad = lane >> 4, l15 = lane & 15;
  const int row0 = blockIdx.x * 64 + w * 16;

  const __hip_bfloat16* pa = xh + (size_t)(row0 + l15) * 64 + quad * 8;
  const __hip_bfloat16* pb = xl + (size_t)(row0 + l15) * 64 + quad * 8;
  const bf16x8 ah0 = *(const bf16x8*)(pa);
  const bf16x8 ah1 = *(const bf16x8*)(pa + 32);
  const bf16x8 al0 = *(const bf16x8*)(pb);
  const bf16x8 al1 = *(const bf16x8*)(pb + 32);

#pragma unroll
  for (int ct = 0; ct < 8; ++ct) {
    const __hip_bfloat16* qh = gh + (size_t)(ct * 16 + l15) * 64 + quad * 8;
    const __hip_bfloat16* ql = gl + (size_t)(ct * 16 + l15) * 64 + quad * 8;
    bf16x8 bh0 = *(const bf16x8*)(qh);
    bf16x8 bh1 = *(const bf16x8*)(qh + 32);
    bf16x8 bl0 = *(const bf16x8*)(ql);
    bf16x8 bl1 = *(const bf16x8*)(ql + 32);
    f32x4 m1 = { 0.f, 0.f, 0.f, 0.f };
    f32x4 m2 = m1, m3 = m1, m4 = m1, m5 = m1, m6 = m1;
    m1 = __builtin_amdgcn_mfma_f32_16x16x32_bf16(ah0, bh0, m1, 0, 0, 0);
    m2 = __builtin_amdgcn_mfma_f32_16x16x32_bf16(ah1, bh1, m2, 0, 0, 0);
    m3 = __builtin_amdgcn_mfma_f32_16x16x32_bf16(ah0, bl0, m3, 0, 0, 0);
    m4 = __builtin_amdgcn_mfma_f32_16x16x32_bf16(ah1, bl1, m4, 0, 0, 0);
    m5 = __builtin_amdgcn_mfma_f32_16x16x32_bf16(al0, bh0, m5, 0, 0, 0);
    m6 = __builtin_amdgcn_mfma_f32_16x16x32_bf16(al1, bh1, m6, 0, 0, 0);
    if (ct < 4) {
#pragma unroll
      for (int i = 0; i < 4; ++i) {
        float s = ((m1[i] + m2[i]) + (m3[i] + m4[i])) + (m5[i] + m6[i]);
        P[(size_t)(row0 + quad * 4 + i) * 64 + ct * 16 + l15] = s;
      }
    } else {
      const float bq = bb[(ct - 4) * 16 + l15];
#pragma unroll
      for (int i = 0; i < 4; ++i) {
        float s = ((m1[i] + m2[i]) + (m3[i] + m4[i])) + (m5[i] + m6[i]);
        Q[(size_t)(row0 + quad * 4 + i) * 64 + (ct - 4) * 16 + l15] = s + bq;
      }
    }
  }
}

// ---------------------------------------------------------------------------
// F: y[n][o] = relu(max_k (Q[n][o] + P[knn[n][k]][o]))
// 512 threads (8 waves x 8 rows).
// ---------------------------------------------------------------------------
__global__ __launch_bounds__(512) void k_out(const float* __restrict__ P,
                                             const float* __restrict__ Q,
                                             const int* __restrict__ knn,
                                             float* __restrict__ out) {
  __shared__ float tile[64][65];
  const int b    = blockIdx.y;
  const int n0   = blockIdx.x * 64;
  const int wave = threadIdx.x >> 6;              // 0..7
  const int lane = threadIdx.x & 63;
#pragma unroll 1
  for (int i = 0; i < 8; ++i) {
    const int nl = wave * 8 + i;
    const int gn = b * NPTS + n0 + nl;
    float acc = -1e30f;
    const float qv = Q[(size_t)gn * 64 + lane];
    const int* id = knn + (size_t)gn * 16;
#pragma unroll
    for (int k = 0; k < 16; ++k) {
      int m = id[k];
      float p = P[((size_t)b * NPTS + m) * 64 + lane];
      acc = fmaxf(acc, qv + p);
    }
    tile[nl][lane] = fmaxf(acc, 0.f);
  }
  __syncthreads();
#pragma unroll
  for (int i = 0; i < 8; ++i) {
    const int o = i * 8 + wave;
    out[((size_t)b * 64 + o) * NPTS + n0 + lane] = tile[lane][o];
  }
}

// ---------------------------------------------------------------------------
extern "C" void kernel_launch(void* const* d_in, const int* in_sizes, int n_in,
                              void* d_out, int out_size, void* d_ws, size_t ws_size,
                              hipStream_t stream) {
  const float* x  = (const float*)d_in[0];
  const float* W1 = (const float*)d_in[1];
  const float* b1 = (const float*)d_in[2];
  const float* W2 = (const float*)d_in[3];
  const float* b2 = (const float*)d_in[4];
  float* out = (float*)d_out;

  // workspace ~27.6 MB (PART region kept at 64 u32/row so Pm overlay fits)
  float* ws = (float*)d_ws;
  const size_t NPT_ALL = (size_t)NB * NPTS;                 // 32768
  float*          XT   = ws;                                // 8.39 MB
  float*          SQ   = XT + NPT_ALL * 64;                 // 0.13 MB
  float*          SQN  = SQ + NPT_ALL;                      // 0.13 MB (scaled)
  __hip_bfloat16* XH   = (__hip_bfloat16*)(SQN + NPT_ALL);  // 4.19 MB
  __hip_bfloat16* XL   = XH + NPT_ALL * 64;                 // 4.19 MB
  unsigned*       PART = (unsigned*)(XL + NPT_ALL * 64);    // 8.39 MB region
  int*            KNN  = (int*)(PART + NPT_ALL * 64);       // 2.10 MB
  __hip_bfloat16* GH   = (__hip_bfloat16*)(KNN + NPT_ALL * 16); // 16 KB
  __hip_bfloat16* GL   = GH + 128 * 64;                     // 16 KB
  float*          BB   = (float*)(GL + 128 * 64);           // 256 B
  float*          Pm   = (float*)PART;  // overlay: PART dead after k_mr
  float*          Qm   = XT;            // overlay: XT dead after k_mr (race-free)

  k_prep <<<dim3(NPTS / 64 + 1, NB), 256, 0, stream>>>(x, W1, b1, W2, b2,
                                                       XT, XH, XL, SQ, SQN,
                                                       GH, GL, BB);
  k_knn  <<<dim3(NPTS / 64, NQ, NB), KNN_T, 0, stream>>>(XH, SQN, PART);
  k_mr   <<<dim3(NPT_ALL / 8), 256, 0, stream>>>(PART, XT, SQ, KNN);
  k_pq   <<<dim3(NPT_ALL / 64), 256, 0, stream>>>(XH, XL, GH, GL, BB, Pm, Qm);
  k_out  <<<dim3(NPTS / 64, NB), 512, 0, stream>>>(Pm, Qm, KNN, out);
}